// Round 5
// baseline (710.412 us; speedup 1.0000x reference)
//
#include <hip/hip_runtime.h>

#define N_NODES 100000
#define N_EDGES 1600000
#define NEG_SLOPE 0.2f

typedef __bf16 bf16x8 __attribute__((ext_vector_type(8)));
typedef float f32x4 __attribute__((ext_vector_type(4)));

__device__ inline unsigned short f2bf(float f) {
    union { float f; unsigned u; } x; x.f = f;
    unsigned r = x.u + 0x7fffu + ((x.u >> 16) & 1u);   // round-to-nearest-even
    return (unsigned short)(r >> 16);
}
__device__ inline float rlanef(float v, int l) {       // uniform readlane -> SGPR
    union { float f; int i; } x; x.f = v;
    x.i = __builtin_amdgcn_readlane(x.i, l);
    return x.f;
}

// ---- W_src / W_dst -> bf16, pre-swizzled into MFMA B-fragment order --------
// For element (k, n): lane = ((k&31)>>3)*16 + (n&15), j = k&7  (validated R1/R3)
// Both layouts: [ct(16)][ks(8)][lane(64)][j(8)]   (ct = n>>4, ks = k>>5)
__global__ __launch_bounds__(256) void cvt_w_k(const float* __restrict__ Ws,
                                               const float* __restrict__ Wd,
                                               unsigned short* __restrict__ Wsw_src,
                                               unsigned short* __restrict__ Wsw_dst) {
    int idx = blockIdx.x * 256 + threadIdx.x;        // 0..131071
    int sel = idx >> 16;
    int r = idx & 65535;
    int k = r >> 8, n = r & 255;
    int ct = n >> 4, nl = n & 15;
    int lane = ((k & 31) >> 3) * 16 + nl, j = k & 7;
    int ks = k >> 5;
    unsigned short v = f2bf((sel == 0 ? Ws : Wd)[k * 256 + n]);
    (sel == 0 ? Wsw_src : Wsw_dst)[(ct * 8 + ks) * 512 + lane * 8 + j] = v;
}

// ---- [Wa_src|Wa_dst|0] -> bf16 B-fragment [ks(8)][lane(64)][j(8)] ----------
// cols: n<4 -> Wa_src[:,n], n in 4..7 -> Wa_dst[:,n-4], n>=8 -> 0
__global__ void cvt_wa_k(const float* __restrict__ Was,
                         const float* __restrict__ Wad,
                         unsigned short* __restrict__ Wa_sw) {
    int idx = blockIdx.x * 256 + threadIdx.x;        // 0..4095
    int j = idx & 7, lane = (idx >> 3) & 63, ks = idx >> 9;
    int n = lane & 15, k = ks * 32 + (lane >> 4) * 8 + j;
    float v = n < 4 ? Was[k * 4 + n] : (n < 8 ? Wad[k * 4 + (n - 4)] : 0.f);
    Wa_sw[idx] = f2bf(v);
}

// ---- attention logit projections via MFMA: a_src[N,4], a_dst[N,4] ----------
// Wave = 16-node tile; 8 MFMAs -> D[16 nodes][16 cols], cols 0..3=a_src, 4..7=a_dst
__global__ __launch_bounds__(256) void aproj_k(const float* __restrict__ feat,
                                               const unsigned short* __restrict__ Wa_sw,
                                               float* __restrict__ a_src,
                                               float* __restrict__ a_dst) {
    int wave = threadIdx.x >> 6, lane = threadIdx.x & 63;
    int quad = lane >> 4, l16 = lane & 15;
    int row_strip = (blockIdx.x * 4 + wave) * 16;
    int arow = row_strip + l16;
    if (arow >= N_NODES) arow = N_NODES - 1;         // clamp loads; stores guarded
    const float* arow_p = feat + (size_t)arow * 256;
    const bf16x8* Wa8 = (const bf16x8*)Wa_sw;
    f32x4 acc = {0.f, 0.f, 0.f, 0.f};
    #pragma unroll
    for (int ks = 0; ks < 8; ++ks) {
        int k0 = ks * 32 + quad * 8;
        float4 f0 = *(const float4*)(arow_p + k0);
        float4 f1 = *(const float4*)(arow_p + k0 + 4);
        union { unsigned short u[8]; bf16x8 v; } cv;
        cv.u[0] = f2bf(f0.x); cv.u[1] = f2bf(f0.y);
        cv.u[2] = f2bf(f0.z); cv.u[3] = f2bf(f0.w);
        cv.u[4] = f2bf(f1.x); cv.u[5] = f2bf(f1.y);
        cv.u[6] = f2bf(f1.z); cv.u[7] = f2bf(f1.w);
        acc = __builtin_amdgcn_mfma_f32_16x16x32_bf16(cv.v, Wa8[ks * 64 + lane], acc, 0, 0, 0);
    }
    #pragma unroll
    for (int r = 0; r < 4; ++r) {                    // row = quad*4+r, col = l16
        int n = row_strip + quad * 4 + r;
        if (n < N_NODES) {
            if (l16 < 4)      a_src[n * 4 + l16] = acc[r];
            else if (l16 < 8) a_dst[n * 4 + (l16 - 4)] = acc[r];
        }
    }
}

// ---- CSR row pointers from sorted dst --------------------------------------
__global__ void rowptr_k(const int* __restrict__ dst, int* __restrict__ rp) {
    int n = blockIdx.x * 256 + threadIdx.x;
    if (n > N_NODES) return;
    int lo = 0, hi = N_EDGES;                        // first i with dst[i] >= n
    while (lo < hi) { int mid = (lo + hi) >> 1; if (dst[mid] < n) lo = mid + 1; else hi = mid; }
    rp[n] = lo;
}

// ---- fused: edge softmax + feature aggregation + MFMA proj + h_dst ---------
// Block: 256 thr (4 waves), 4 dst nodes, ONE node per wave.
// Fast path (deg<=64, ~all nodes): single (src,a_src) load round held in regs;
// butterfly max -> exp -> butterfly sum; per-edge (s,w) broadcast by readlane.
// Proj: wave h -> out cols h*64..h*64+63 via MFMA (A rows 4..15 are duplicates
// of rows 0..3 -- D rows >=4 simply not stored; A-row garbage can't pollute
// stored rows). out written exactly once.
__global__ __launch_bounds__(256, 8) void agg_k(const int* __restrict__ src,
                                                const int* __restrict__ rp,
                                                const float* __restrict__ a_src,
                                                const float* __restrict__ a_dst,
                                                const float* __restrict__ feat,
                                                const unsigned short* __restrict__ Wsw_src,
                                                const unsigned short* __restrict__ Wsw_dst,
                                                const float* __restrict__ b_dst,
                                                float* __restrict__ out) {
    __shared__ unsigned short G[4 * 32 * 5 * 8];     // 10,240 B (m padded 4->5)
    int tid = threadIdx.x, wave = tid >> 6, lane = tid & 63;
    int base = blockIdx.x * 4;
    int node = base + wave;
    int r0 = rp[node], r1 = rp[node + 1];
    int deg = r1 - r0;
    f32x4 g0 = {0.f,0.f,0.f,0.f}, g1 = g0, g2 = g0, g3 = g0;

    if (deg > 0 && deg <= 64) {
        // ---- fast path: one load round ----
        float4 adv = *(const float4*)(a_dst + node * 4);
        bool act = lane < deg;
        int s = 0;
        float4 av = {0.f, 0.f, 0.f, 0.f};
        if (act) {
            s = src[r0 + lane];
            av = *(const float4*)(a_src + s * 4);
        }
        float e0 = av.x + adv.x; e0 = e0 > 0.f ? e0 : NEG_SLOPE * e0;
        float e1 = av.y + adv.y; e1 = e1 > 0.f ? e1 : NEG_SLOPE * e1;
        float e2 = av.z + adv.z; e2 = e2 > 0.f ? e2 : NEG_SLOPE * e2;
        float e3 = av.w + adv.w; e3 = e3 > 0.f ? e3 : NEG_SLOPE * e3;
        if (!act) { e0 = e1 = e2 = e3 = -1e30f; }
        float m0 = e0, m1 = e1, m2 = e2, m3 = e3;
        #pragma unroll
        for (int off = 32; off > 0; off >>= 1) {
            m0 = fmaxf(m0, __shfl_xor(m0, off));
            m1 = fmaxf(m1, __shfl_xor(m1, off));
            m2 = fmaxf(m2, __shfl_xor(m2, off));
            m3 = fmaxf(m3, __shfl_xor(m3, off));
        }
        float w0 = act ? __expf(e0 - m0) : 0.f;
        float w1 = act ? __expf(e1 - m1) : 0.f;
        float w2 = act ? __expf(e2 - m2) : 0.f;
        float w3 = act ? __expf(e3 - m3) : 0.f;
        float d0 = w0, d1 = w1, d2 = w2, d3 = w3;
        #pragma unroll
        for (int off = 32; off > 0; off >>= 1) {
            d0 += __shfl_xor(d0, off); d1 += __shfl_xor(d1, off);
            d2 += __shfl_xor(d2, off); d3 += __shfl_xor(d3, off);
        }
        w0 *= 1.f / d0; w1 *= 1.f / d1; w2 *= 1.f / d2; w3 *= 1.f / d3;
        for (int j = 0; j < deg; ++j) {
            int sj   = __builtin_amdgcn_readlane(s, j);
            float wx = rlanef(w0, j), wy = rlanef(w1, j);
            float wz = rlanef(w2, j), ww = rlanef(w3, j);
            f32x4 f = *(const f32x4*)(feat + (size_t)sj * 256 + lane * 4);
            g0 += wx * f; g1 += wy * f;
            g2 += wz * f; g3 += ww * f;
        }
    } else if (deg > 64) {
        // ---- fallback: chunked 3-pass (rare; deg ~ Poisson(16)) ----
        float4 adv = *(const float4*)(a_dst + node * 4);
        float m0 = -1e30f, m1 = -1e30f, m2 = -1e30f, m3 = -1e30f;
        for (int e = r0 + lane; e < r1; e += 64) {
            int s = src[e];
            float4 av = *(const float4*)(a_src + s * 4);
            float e0 = av.x + adv.x; e0 = e0 > 0.f ? e0 : NEG_SLOPE * e0;
            float e1 = av.y + adv.y; e1 = e1 > 0.f ? e1 : NEG_SLOPE * e1;
            float e2 = av.z + adv.z; e2 = e2 > 0.f ? e2 : NEG_SLOPE * e2;
            float e3 = av.w + adv.w; e3 = e3 > 0.f ? e3 : NEG_SLOPE * e3;
            m0 = fmaxf(m0, e0); m1 = fmaxf(m1, e1);
            m2 = fmaxf(m2, e2); m3 = fmaxf(m3, e3);
        }
        #pragma unroll
        for (int off = 32; off > 0; off >>= 1) {
            m0 = fmaxf(m0, __shfl_xor(m0, off));
            m1 = fmaxf(m1, __shfl_xor(m1, off));
            m2 = fmaxf(m2, __shfl_xor(m2, off));
            m3 = fmaxf(m3, __shfl_xor(m3, off));
        }
        float d0 = 0.f, d1 = 0.f, d2 = 0.f, d3 = 0.f;
        for (int e = r0 + lane; e < r1; e += 64) {
            int s = src[e];
            float4 av = *(const float4*)(a_src + s * 4);
            float e0 = av.x + adv.x; e0 = e0 > 0.f ? e0 : NEG_SLOPE * e0;
            float e1 = av.y + adv.y; e1 = e1 > 0.f ? e1 : NEG_SLOPE * e1;
            float e2 = av.z + adv.z; e2 = e2 > 0.f ? e2 : NEG_SLOPE * e2;
            float e3 = av.w + adv.w; e3 = e3 > 0.f ? e3 : NEG_SLOPE * e3;
            d0 += __expf(e0 - m0); d1 += __expf(e1 - m1);
            d2 += __expf(e2 - m2); d3 += __expf(e3 - m3);
        }
        #pragma unroll
        for (int off = 32; off > 0; off >>= 1) {
            d0 += __shfl_xor(d0, off); d1 += __shfl_xor(d1, off);
            d2 += __shfl_xor(d2, off); d3 += __shfl_xor(d3, off);
        }
        float i0 = 1.f / d0, i1 = 1.f / d1, i2 = 1.f / d2, i3 = 1.f / d3;
        for (int c0 = r0; c0 < r1; c0 += 64) {
            int cnt = min(64, r1 - c0);
            int s = 0; float w0 = 0.f, w1 = 0.f, w2 = 0.f, w3 = 0.f;
            if (lane < cnt) {
                s = src[c0 + lane];
                float4 av = *(const float4*)(a_src + s * 4);
                float e0 = av.x + adv.x; e0 = e0 > 0.f ? e0 : NEG_SLOPE * e0;
                float e1 = av.y + adv.y; e1 = e1 > 0.f ? e1 : NEG_SLOPE * e1;
                float e2 = av.z + adv.z; e2 = e2 > 0.f ? e2 : NEG_SLOPE * e2;
                float e3 = av.w + adv.w; e3 = e3 > 0.f ? e3 : NEG_SLOPE * e3;
                w0 = __expf(e0 - m0) * i0; w1 = __expf(e1 - m1) * i1;
                w2 = __expf(e2 - m2) * i2; w3 = __expf(e3 - m3) * i3;
            }
            for (int j = 0; j < cnt; ++j) {
                int sj   = __builtin_amdgcn_readlane(s, j);
                float wx = rlanef(w0, j), wy = rlanef(w1, j);
                float wz = rlanef(w2, j), ww = rlanef(w3, j);
                f32x4 f = *(const f32x4*)(feat + (size_t)sj * 256 + lane * 4);
                g0 += wx * f; g1 += wy * f;
                g2 += wz * f; g3 += ww * f;
            }
        }
    }

    // write g (zeros if no edges): lane owns cols lane*4..+3; m = wave
    {
        int g8 = lane >> 1, off4 = (lane & 1) * 4;
        ushort4 u;
        u.x = f2bf(g0[0]); u.y = f2bf(g0[1]); u.z = f2bf(g0[2]); u.w = f2bf(g0[3]);
        *(ushort4*)&G[((0 * 32 + g8) * 5 + wave) * 8 + off4] = u;
        u.x = f2bf(g1[0]); u.y = f2bf(g1[1]); u.z = f2bf(g1[2]); u.w = f2bf(g1[3]);
        *(ushort4*)&G[((1 * 32 + g8) * 5 + wave) * 8 + off4] = u;
        u.x = f2bf(g2[0]); u.y = f2bf(g2[1]); u.z = f2bf(g2[2]); u.w = f2bf(g2[3]);
        *(ushort4*)&G[((2 * 32 + g8) * 5 + wave) * 8 + off4] = u;
        u.x = f2bf(g3[0]); u.y = f2bf(g3[1]); u.z = f2bf(g3[2]); u.w = f2bf(g3[3]);
        *(ushort4*)&G[((3 * 32 + g8) * 5 + wave) * 8 + off4] = u;
    }
    __syncthreads();

    // ---------------- projection phase: wave = head = out-col slice ----------
    int h = wave, quad = lane >> 4, l16 = lane & 15;
    f32x4 acc[4];
    #pragma unroll
    for (int c = 0; c < 4; ++c) acc[c] = (f32x4){0.f, 0.f, 0.f, 0.f};

    // part 1: g @ W_src[head h]  (A from G; rows 4..15 duplicate rows 0..3)
    const bf16x8* Ws8 = (const bf16x8*)Wsw_src;
    #pragma unroll
    for (int ks = 0; ks < 8; ++ks) {
        bf16x8 a = *(const bf16x8*)&G[((h * 32 + ks * 4 + quad) * 5 + (l16 & 3)) * 8];
        #pragma unroll
        for (int ct = 0; ct < 4; ++ct)
            acc[ct] = __builtin_amdgcn_mfma_f32_16x16x32_bf16(
                a, Ws8[((h * 4 + ct) * 8 + ks) * 64 + lane], acc[ct], 0, 0, 0);
    }
    // part 2: feat[dst rows] @ W_dst[cols h*64..]  (A rows duplicated likewise)
    const float* arow_p = feat + (size_t)(base + (l16 & 3)) * 256;
    const bf16x8* Wd8 = (const bf16x8*)Wsw_dst;
    #pragma unroll
    for (int ks = 0; ks < 8; ++ks) {
        int k0 = ks * 32 + quad * 8;
        float4 f0 = *(const float4*)(arow_p + k0);
        float4 f1 = *(const float4*)(arow_p + k0 + 4);
        union { unsigned short u[8]; bf16x8 v; } cv;
        cv.u[0] = f2bf(f0.x); cv.u[1] = f2bf(f0.y);
        cv.u[2] = f2bf(f0.z); cv.u[3] = f2bf(f0.w);
        cv.u[4] = f2bf(f1.x); cv.u[5] = f2bf(f1.y);
        cv.u[6] = f2bf(f1.z); cv.u[7] = f2bf(f1.w);
        #pragma unroll
        for (int ct = 0; ct < 4; ++ct)
            acc[ct] = __builtin_amdgcn_mfma_f32_16x16x32_bf16(
                cv.v, Wd8[((h * 4 + ct) * 8 + ks) * 64 + lane], acc[ct], 0, 0, 0);
    }
    // store: rows 0..3 live in quad 0 (row = quad*4+reg); out written once
    if (quad == 0) {
        #pragma unroll
        for (int ct = 0; ct < 4; ++ct) {
            int col = h * 64 + ct * 16 + l16;
            float b = b_dst[col];
            #pragma unroll
            for (int r = 0; r < 4; ++r)
                out[(size_t)(base + r) * 256 + col] = acc[ct][r] + b;
        }
    }
}

extern "C" void kernel_launch(void* const* d_in, const int* in_sizes, int n_in,
                              void* d_out, int out_size, void* d_ws, size_t ws_size,
                              hipStream_t stream) {
    const float* feat   = (const float*)d_in[0];
    const float* W_src  = (const float*)d_in[1];
    const float* W_dst  = (const float*)d_in[2];
    const float* b_dst  = (const float*)d_in[3];
    const float* Wa_src = (const float*)d_in[4];
    const float* Wa_dst = (const float*)d_in[5];
    const int*   src    = (const int*)d_in[6];
    const int*   dst    = (const int*)d_in[7];
    float* out = (float*)d_out;

    // ws footprint: 3,870,340 B (known-good scale from R3; ws_size < 55 MB)
    char* ws = (char*)d_ws;
    unsigned short* Wsw_src = (unsigned short*)(ws);               // 131,072 B
    unsigned short* Wsw_dst = (unsigned short*)(ws + 131072);      // 131,072 B
    unsigned short* Wa_sw   = (unsigned short*)(ws + 262144);      //   8,192 B
    float* a_src            = (float*)(ws + 270336);               // 1,600,000 B
    float* a_dst            = (float*)(ws + 1870336);              // 1,600,000 B
    int*   rp               = (int*)(ws + 3470336);                // 400,004 B

    hipLaunchKernelGGL(cvt_w_k,  dim3(512),   dim3(256), 0, stream, W_src, W_dst, Wsw_src, Wsw_dst);
    hipLaunchKernelGGL(cvt_wa_k, dim3(16),    dim3(256), 0, stream, Wa_src, Wa_dst, Wa_sw);
    hipLaunchKernelGGL(aproj_k,  dim3(1563),  dim3(256), 0, stream, feat, Wa_sw, a_src, a_dst);
    hipLaunchKernelGGL(rowptr_k, dim3(391),   dim3(256), 0, stream, dst, rp);
    hipLaunchKernelGGL(agg_k,    dim3(25000), dim3(256), 0, stream, src, rp, a_src, a_dst,
                       feat, Wsw_src, Wsw_dst, b_dst, out);
}

// Round 6
// 469.733 us; speedup vs baseline: 1.5124x; 1.5124x over previous
//
#include <hip/hip_runtime.h>

#define N_NODES 100000
#define N_EDGES 1600000
#define NEG_SLOPE 0.2f

typedef __bf16 bf16x8 __attribute__((ext_vector_type(8)));
typedef float f32x4 __attribute__((ext_vector_type(4)));

__device__ inline unsigned short f2bf(float f) {
    union { float f; unsigned u; } x; x.f = f;
    unsigned r = x.u + 0x7fffu + ((x.u >> 16) & 1u);   // round-to-nearest-even
    return (unsigned short)(r >> 16);
}
__device__ inline float rlanef(float v, int l) {       // uniform readlane -> SGPR
    union { float f; int i; } x; x.f = v;
    x.i = __builtin_amdgcn_readlane(x.i, l);
    return x.f;
}

// ---- W_src / W_dst -> bf16, pre-swizzled into MFMA B-fragment order --------
// For element (k, n): lane = ((k&31)>>3)*16 + (n&15), j = k&7  (validated R1/R3)
// Both layouts: [ct(16)][ks(8)][lane(64)][j(8)]   (ct = n>>4, ks = k>>5)
__global__ __launch_bounds__(256) void cvt_w_k(const float* __restrict__ Ws,
                                               const float* __restrict__ Wd,
                                               unsigned short* __restrict__ Wsw_src,
                                               unsigned short* __restrict__ Wsw_dst) {
    int idx = blockIdx.x * 256 + threadIdx.x;        // 0..131071
    int sel = idx >> 16;
    int r = idx & 65535;
    int k = r >> 8, n = r & 255;
    int ct = n >> 4, nl = n & 15;
    int lane = ((k & 31) >> 3) * 16 + nl, j = k & 7;
    int ks = k >> 5;
    unsigned short v = f2bf((sel == 0 ? Ws : Wd)[k * 256 + n]);
    (sel == 0 ? Wsw_src : Wsw_dst)[(ct * 8 + ks) * 512 + lane * 8 + j] = v;
}

// ---- [Wa_src|Wa_dst|0] -> bf16 B-fragment [ks(8)][lane(64)][j(8)] ----------
__global__ void cvt_wa_k(const float* __restrict__ Was,
                         const float* __restrict__ Wad,
                         unsigned short* __restrict__ Wa_sw) {
    int idx = blockIdx.x * 256 + threadIdx.x;        // 0..4095
    int j = idx & 7, lane = (idx >> 3) & 63, ks = idx >> 9;
    int n = lane & 15, k = ks * 32 + (lane >> 4) * 8 + j;
    float v = n < 4 ? Was[k * 4 + n] : (n < 8 ? Wad[k * 4 + (n - 4)] : 0.f);
    Wa_sw[idx] = f2bf(v);
}

// ---- attention logit projections via MFMA: a_src[N,4], a_dst[N,4] ----------
__global__ __launch_bounds__(256) void aproj_k(const float* __restrict__ feat,
                                               const unsigned short* __restrict__ Wa_sw,
                                               float* __restrict__ a_src,
                                               float* __restrict__ a_dst) {
    int wave = threadIdx.x >> 6, lane = threadIdx.x & 63;
    int quad = lane >> 4, l16 = lane & 15;
    int row_strip = (blockIdx.x * 4 + wave) * 16;
    int arow = row_strip + l16;
    if (arow >= N_NODES) arow = N_NODES - 1;         // clamp loads; stores guarded
    const float* arow_p = feat + (size_t)arow * 256;
    const bf16x8* Wa8 = (const bf16x8*)Wa_sw;
    f32x4 acc = {0.f, 0.f, 0.f, 0.f};
    #pragma unroll
    for (int ks = 0; ks < 8; ++ks) {
        int k0 = ks * 32 + quad * 8;
        float4 f0 = *(const float4*)(arow_p + k0);
        float4 f1 = *(const float4*)(arow_p + k0 + 4);
        union { unsigned short u[8]; bf16x8 v; } cv;
        cv.u[0] = f2bf(f0.x); cv.u[1] = f2bf(f0.y);
        cv.u[2] = f2bf(f0.z); cv.u[3] = f2bf(f0.w);
        cv.u[4] = f2bf(f1.x); cv.u[5] = f2bf(f1.y);
        cv.u[6] = f2bf(f1.z); cv.u[7] = f2bf(f1.w);
        acc = __builtin_amdgcn_mfma_f32_16x16x32_bf16(cv.v, Wa8[ks * 64 + lane], acc, 0, 0, 0);
    }
    #pragma unroll
    for (int r = 0; r < 4; ++r) {                    // row = quad*4+r, col = l16
        int n = row_strip + quad * 4 + r;
        if (n < N_NODES) {
            if (l16 < 4)      a_src[n * 4 + l16] = acc[r];
            else if (l16 < 8) a_dst[n * 4 + (l16 - 4)] = acc[r];
        }
    }
}

// ---- CSR row pointers from sorted dst --------------------------------------
__global__ void rowptr_k(const int* __restrict__ dst, int* __restrict__ rp) {
    int n = blockIdx.x * 256 + threadIdx.x;
    if (n > N_NODES) return;
    int lo = 0, hi = N_EDGES;                        // first i with dst[i] >= n
    while (lo < hi) { int mid = (lo + hi) >> 1; if (dst[mid] < n) lo = mid + 1; else hi = mid; }
    rp[n] = lo;
}

// ---- fused: edge softmax + feature aggregation + MFMA proj + h_dst ---------
// Block: 512 thr (8 waves), 16 dst nodes; wave w gathers nodes w*2, w*2+1.
// Fast path (deg<=64): ONE (src,a_src) load round; butterfly max/sum in regs;
// gather loop unrolled x4 (4 feat-row loads in flight — R4/R5 exposed full
// latency per edge). feat[dst] tile staged ONCE to LDS F (bf16 frag layout);
// projection wave w: head h=w>>1, ct pair (w&1)*2: acc = g@W_src + F@W_dst.
__global__ __launch_bounds__(512, 6) void agg_k(const int* __restrict__ src,
                                                const int* __restrict__ rp,
                                                const float* __restrict__ a_src,
                                                const float* __restrict__ a_dst,
                                                const float* __restrict__ feat,
                                                const unsigned short* __restrict__ Wsw_src,
                                                const unsigned short* __restrict__ Wsw_dst,
                                                const float* __restrict__ b_dst,
                                                float* __restrict__ out) {
    __shared__ unsigned short G[4 * 32 * 17 * 8];    // 34,816 B (m padded 16->17)
    __shared__ unsigned short F[32 * 17 * 8];        //  8,704 B feat-dst tile
    int tid = threadIdx.x, wave = tid >> 6, lane = tid & 63;
    int base = blockIdx.x * 16;

    // ---- stage F = feat[base..base+15][:] as bf16 A-fragments (coalesced) ----
    #pragma unroll
    for (int e = tid; e < 1024; e += 512) {
        int m = e >> 6, k0 = (e & 63) * 4;
        float4 f = *(const float4*)(feat + (size_t)(base + m) * 256 + k0);
        ushort4 u;
        u.x = f2bf(f.x); u.y = f2bf(f.y); u.z = f2bf(f.z); u.w = f2bf(f.w);
        int ks = k0 >> 5, quad = (k0 >> 3) & 3, jb = k0 & 7;   // jb in {0,4}
        *(ushort4*)&F[((ks * 4 + quad) * 17 + m) * 8 + jb] = u;
    }

    // ---------------- gather phase: 2 nodes per wave ----------------
    for (int i = 0; i < 2; ++i) {
        int m = wave * 2 + i;
        int node = base + m;
        int r0 = rp[node], r1 = rp[node + 1];
        int deg = r1 - r0;
        f32x4 g0 = {0.f,0.f,0.f,0.f}, g1 = g0, g2 = g0, g3 = g0;

        if (deg > 0 && deg <= 64) {
            // ---- fast path: one load round ----
            float4 adv = *(const float4*)(a_dst + node * 4);
            bool act = lane < deg;
            int s = 0;
            float4 av = {0.f, 0.f, 0.f, 0.f};
            if (act) {
                s = src[r0 + lane];
                av = *(const float4*)(a_src + s * 4);
            }
            float e0 = av.x + adv.x; e0 = e0 > 0.f ? e0 : NEG_SLOPE * e0;
            float e1 = av.y + adv.y; e1 = e1 > 0.f ? e1 : NEG_SLOPE * e1;
            float e2 = av.z + adv.z; e2 = e2 > 0.f ? e2 : NEG_SLOPE * e2;
            float e3 = av.w + adv.w; e3 = e3 > 0.f ? e3 : NEG_SLOPE * e3;
            if (!act) { e0 = e1 = e2 = e3 = -1e30f; }
            float m0 = e0, m1 = e1, m2 = e2, m3 = e3;
            #pragma unroll
            for (int off = 32; off > 0; off >>= 1) {
                m0 = fmaxf(m0, __shfl_xor(m0, off));
                m1 = fmaxf(m1, __shfl_xor(m1, off));
                m2 = fmaxf(m2, __shfl_xor(m2, off));
                m3 = fmaxf(m3, __shfl_xor(m3, off));
            }
            float w0 = act ? __expf(e0 - m0) : 0.f;
            float w1 = act ? __expf(e1 - m1) : 0.f;
            float w2 = act ? __expf(e2 - m2) : 0.f;
            float w3 = act ? __expf(e3 - m3) : 0.f;
            float d0 = w0, d1 = w1, d2 = w2, d3 = w3;
            #pragma unroll
            for (int off = 32; off > 0; off >>= 1) {
                d0 += __shfl_xor(d0, off); d1 += __shfl_xor(d1, off);
                d2 += __shfl_xor(d2, off); d3 += __shfl_xor(d3, off);
            }
            w0 *= 1.f / d0; w1 *= 1.f / d1; w2 *= 1.f / d2; w3 *= 1.f / d3;
            // gather, 4 loads in flight
            int j = 0;
            for (; j + 4 <= deg; j += 4) {
                int s0 = __builtin_amdgcn_readlane(s, j);
                int s1 = __builtin_amdgcn_readlane(s, j + 1);
                int s2 = __builtin_amdgcn_readlane(s, j + 2);
                int s3 = __builtin_amdgcn_readlane(s, j + 3);
                f32x4 f0 = *(const f32x4*)(feat + (size_t)s0 * 256 + lane * 4);
                f32x4 f1 = *(const f32x4*)(feat + (size_t)s1 * 256 + lane * 4);
                f32x4 f2 = *(const f32x4*)(feat + (size_t)s2 * 256 + lane * 4);
                f32x4 f3 = *(const f32x4*)(feat + (size_t)s3 * 256 + lane * 4);
                float a0 = rlanef(w0, j),   b0 = rlanef(w1, j),   c0 = rlanef(w2, j),   x0 = rlanef(w3, j);
                float a1 = rlanef(w0, j+1), b1 = rlanef(w1, j+1), c1 = rlanef(w2, j+1), x1 = rlanef(w3, j+1);
                float a2 = rlanef(w0, j+2), b2 = rlanef(w1, j+2), c2 = rlanef(w2, j+2), x2 = rlanef(w3, j+2);
                float a3 = rlanef(w0, j+3), b3 = rlanef(w1, j+3), c3 = rlanef(w2, j+3), x3 = rlanef(w3, j+3);
                g0 += a0 * f0; g1 += b0 * f0; g2 += c0 * f0; g3 += x0 * f0;
                g0 += a1 * f1; g1 += b1 * f1; g2 += c1 * f1; g3 += x1 * f1;
                g0 += a2 * f2; g1 += b2 * f2; g2 += c2 * f2; g3 += x2 * f2;
                g0 += a3 * f3; g1 += b3 * f3; g2 += c3 * f3; g3 += x3 * f3;
            }
            for (; j < deg; ++j) {
                int sj   = __builtin_amdgcn_readlane(s, j);
                float wx = rlanef(w0, j), wy = rlanef(w1, j);
                float wz = rlanef(w2, j), ww = rlanef(w3, j);
                f32x4 f = *(const f32x4*)(feat + (size_t)sj * 256 + lane * 4);
                g0 += wx * f; g1 += wy * f; g2 += wz * f; g3 += ww * f;
            }
        } else if (deg > 64) {
            // ---- fallback: chunked 3-pass (rare; deg ~ Poisson(16)) ----
            float4 adv = *(const float4*)(a_dst + node * 4);
            float m0 = -1e30f, m1 = -1e30f, m2 = -1e30f, m3 = -1e30f;
            for (int e = r0 + lane; e < r1; e += 64) {
                int s = src[e];
                float4 av = *(const float4*)(a_src + s * 4);
                float e0 = av.x + adv.x; e0 = e0 > 0.f ? e0 : NEG_SLOPE * e0;
                float e1 = av.y + adv.y; e1 = e1 > 0.f ? e1 : NEG_SLOPE * e1;
                float e2 = av.z + adv.z; e2 = e2 > 0.f ? e2 : NEG_SLOPE * e2;
                float e3 = av.w + adv.w; e3 = e3 > 0.f ? e3 : NEG_SLOPE * e3;
                m0 = fmaxf(m0, e0); m1 = fmaxf(m1, e1);
                m2 = fmaxf(m2, e2); m3 = fmaxf(m3, e3);
            }
            #pragma unroll
            for (int off = 32; off > 0; off >>= 1) {
                m0 = fmaxf(m0, __shfl_xor(m0, off));
                m1 = fmaxf(m1, __shfl_xor(m1, off));
                m2 = fmaxf(m2, __shfl_xor(m2, off));
                m3 = fmaxf(m3, __shfl_xor(m3, off));
            }
            float d0 = 0.f, d1 = 0.f, d2 = 0.f, d3 = 0.f;
            for (int e = r0 + lane; e < r1; e += 64) {
                int s = src[e];
                float4 av = *(const float4*)(a_src + s * 4);
                float e0 = av.x + adv.x; e0 = e0 > 0.f ? e0 : NEG_SLOPE * e0;
                float e1 = av.y + adv.y; e1 = e1 > 0.f ? e1 : NEG_SLOPE * e1;
                float e2 = av.z + adv.z; e2 = e2 > 0.f ? e2 : NEG_SLOPE * e2;
                float e3 = av.w + adv.w; e3 = e3 > 0.f ? e3 : NEG_SLOPE * e3;
                d0 += __expf(e0 - m0); d1 += __expf(e1 - m1);
                d2 += __expf(e2 - m2); d3 += __expf(e3 - m3);
            }
            #pragma unroll
            for (int off = 32; off > 0; off >>= 1) {
                d0 += __shfl_xor(d0, off); d1 += __shfl_xor(d1, off);
                d2 += __shfl_xor(d2, off); d3 += __shfl_xor(d3, off);
            }
            float i0 = 1.f / d0, i1 = 1.f / d1, i2 = 1.f / d2, i3 = 1.f / d3;
            for (int c0 = r0; c0 < r1; c0 += 64) {
                int cnt = min(64, r1 - c0);
                int s = 0; float w0 = 0.f, w1 = 0.f, w2 = 0.f, w3 = 0.f;
                if (lane < cnt) {
                    s = src[c0 + lane];
                    float4 av = *(const float4*)(a_src + s * 4);
                    float e0 = av.x + adv.x; e0 = e0 > 0.f ? e0 : NEG_SLOPE * e0;
                    float e1 = av.y + adv.y; e1 = e1 > 0.f ? e1 : NEG_SLOPE * e1;
                    float e2 = av.z + adv.z; e2 = e2 > 0.f ? e2 : NEG_SLOPE * e2;
                    float e3 = av.w + adv.w; e3 = e3 > 0.f ? e3 : NEG_SLOPE * e3;
                    w0 = __expf(e0 - m0) * i0; w1 = __expf(e1 - m1) * i1;
                    w2 = __expf(e2 - m2) * i2; w3 = __expf(e3 - m3) * i3;
                }
                for (int j = 0; j < cnt; ++j) {
                    int sj   = __builtin_amdgcn_readlane(s, j);
                    float wx = rlanef(w0, j), wy = rlanef(w1, j);
                    float wz = rlanef(w2, j), ww = rlanef(w3, j);
                    f32x4 f = *(const f32x4*)(feat + (size_t)sj * 256 + lane * 4);
                    g0 += wx * f; g1 += wy * f; g2 += wz * f; g3 += ww * f;
                }
            }
        }

        // write g (zeros if no edges): lane owns cols lane*4..+3, row m
        int g8 = lane >> 1, off4 = (lane & 1) * 4;
        ushort4 u;
        u.x = f2bf(g0[0]); u.y = f2bf(g0[1]); u.z = f2bf(g0[2]); u.w = f2bf(g0[3]);
        *(ushort4*)&G[((0 * 32 + g8) * 17 + m) * 8 + off4] = u;
        u.x = f2bf(g1[0]); u.y = f2bf(g1[1]); u.z = f2bf(g1[2]); u.w = f2bf(g1[3]);
        *(ushort4*)&G[((1 * 32 + g8) * 17 + m) * 8 + off4] = u;
        u.x = f2bf(g2[0]); u.y = f2bf(g2[1]); u.z = f2bf(g2[2]); u.w = f2bf(g2[3]);
        *(ushort4*)&G[((2 * 32 + g8) * 17 + m) * 8 + off4] = u;
        u.x = f2bf(g3[0]); u.y = f2bf(g3[1]); u.z = f2bf(g3[2]); u.w = f2bf(g3[3]);
        *(ushort4*)&G[((3 * 32 + g8) * 17 + m) * 8 + off4] = u;
    }
    __syncthreads();

    // -------- projection: wave w -> head h = w>>1, ct pair (w&1)*2 ----------
    int h = wave >> 1, hc = (wave & 1) * 2;
    int quad = lane >> 4, l16 = lane & 15;
    f32x4 acc[2];
    acc[0] = (f32x4){0.f, 0.f, 0.f, 0.f};
    acc[1] = (f32x4){0.f, 0.f, 0.f, 0.f};
    const bf16x8* Ws8 = (const bf16x8*)Wsw_src;
    const bf16x8* Wd8 = (const bf16x8*)Wsw_dst;
    #pragma unroll
    for (int ks = 0; ks < 8; ++ks) {
        bf16x8 a1 = *(const bf16x8*)&G[((h * 32 + ks * 4 + quad) * 17 + l16) * 8];
        bf16x8 a2 = *(const bf16x8*)&F[((ks * 4 + quad) * 17 + l16) * 8];
        #pragma unroll
        for (int c = 0; c < 2; ++c) {
            int ct = hc + c;
            acc[c] = __builtin_amdgcn_mfma_f32_16x16x32_bf16(
                a1, Ws8[((h * 4 + ct) * 8 + ks) * 64 + lane], acc[c], 0, 0, 0);
            acc[c] = __builtin_amdgcn_mfma_f32_16x16x32_bf16(
                a2, Wd8[((h * 4 + ct) * 8 + ks) * 64 + lane], acc[c], 0, 0, 0);
        }
    }
    // store: C/D col = lane&15, row = quad*4 + reg; out written exactly once
    #pragma unroll
    for (int c = 0; c < 2; ++c) {
        int col = h * 64 + (hc + c) * 16 + l16;
        float b = b_dst[col];
        #pragma unroll
        for (int r = 0; r < 4; ++r)
            out[(size_t)(base + quad * 4 + r) * 256 + col] = acc[c][r] + b;
    }
}

extern "C" void kernel_launch(void* const* d_in, const int* in_sizes, int n_in,
                              void* d_out, int out_size, void* d_ws, size_t ws_size,
                              hipStream_t stream) {
    const float* feat   = (const float*)d_in[0];
    const float* W_src  = (const float*)d_in[1];
    const float* W_dst  = (const float*)d_in[2];
    const float* b_dst  = (const float*)d_in[3];
    const float* Wa_src = (const float*)d_in[4];
    const float* Wa_dst = (const float*)d_in[5];
    const int*   src    = (const int*)d_in[6];
    const int*   dst    = (const int*)d_in[7];
    float* out = (float*)d_out;

    // ws footprint: 3,870,340 B (known-good scale from R3; ws_size < 55 MB)
    char* ws = (char*)d_ws;
    unsigned short* Wsw_src = (unsigned short*)(ws);               // 131,072 B
    unsigned short* Wsw_dst = (unsigned short*)(ws + 131072);      // 131,072 B
    unsigned short* Wa_sw   = (unsigned short*)(ws + 262144);      //   8,192 B
    float* a_src            = (float*)(ws + 270336);               // 1,600,000 B
    float* a_dst            = (float*)(ws + 1870336);              // 1,600,000 B
    int*   rp               = (int*)(ws + 3470336);                // 400,004 B

    hipLaunchKernelGGL(cvt_w_k,  dim3(512),  dim3(256), 0, stream, W_src, W_dst, Wsw_src, Wsw_dst);
    hipLaunchKernelGGL(cvt_wa_k, dim3(16),   dim3(256), 0, stream, Wa_src, Wa_dst, Wa_sw);
    hipLaunchKernelGGL(aproj_k,  dim3(1563), dim3(256), 0, stream, feat, Wa_sw, a_src, a_dst);
    hipLaunchKernelGGL(rowptr_k, dim3(391),  dim3(256), 0, stream, dst, rp);
    hipLaunchKernelGGL(agg_k,    dim3(6250), dim3(512), 0, stream, src, rp, a_src, a_dst,
                       feat, Wsw_src, Wsw_dst, b_dst, out);
}